// Round 6
// baseline (343.167 us; speedup 1.0000x reference)
//
#include <hip/hip_runtime.h>

// CubePad: x [N*6, C, 256, 256] f32 -> out [N*6, C, 258, 258] f32, pad=1.
// Face order: 0=front, 1=right, 2=back, 3=left, 4=top, 5=down.
// 4 output quads (16B each) per thread: phase 1 issues 4 unconditional clamped
// unaligned float4 loads (4x MLP), phase 2 fixes border quads via scalar
// gather, phase 3 does 4 aligned nontemporal float4 stores.

#define C_  64
#define H_  256
#define W_  256
#define HP  258
#define WP  258
#define FACE_STRIDE (C_ * H_ * W_)     // 4,194,304
#define PLANE_IN  (H_ * W_)            // 65,536
#define PLANE_OUT (HP * WP)            // 66,564 (divisible by 4)
#define P4_PER_PLANE (PLANE_OUT / 4)   // 16,641
#define TOTAL_IN (12 * FACE_STRIDE)    // 50,331,648 elements

typedef float f4  __attribute__((ext_vector_type(4)));              // 16B aligned
typedef float f4u __attribute__((ext_vector_type(4), aligned(4)));  // 4B aligned

__device__ __forceinline__ float value_at(const float* __restrict__ base,
                                          int face, int h, int w) {
#define IN(f, hh, ww) base[(size_t)(f) * FACE_STRIDE + (hh) * W_ + (ww)]
  if (h >= 1 && h <= H_ && w >= 1 && w <= W_) return IN(face, h - 1, w - 1);
  if (h == 0) {                       // top plate (corners via clamp)
    int wi = w - 1; wi = wi < 0 ? 0 : (wi > 255 ? 255 : wi);
    switch (face) {
      case 0:  return IN(4, 255, wi);
      case 1:  return IN(4, 255 - wi, 255);
      case 2:  return IN(4, 0, 255 - wi);
      case 3:  return IN(4, wi, 0);
      case 4:  return IN(2, 0, 255 - wi);
      default: return IN(0, 255, wi);
    }
  }
  if (h == HP - 1) {                  // bottom plate (corners via clamp)
    int wi = w - 1; wi = wi < 0 ? 0 : (wi > 255 ? 255 : wi);
    switch (face) {
      case 0:  return IN(5, 0, wi);
      case 1:  return IN(5, wi, 255);
      case 2:  return IN(5, 255, 255 - wi);
      case 3:  return IN(5, 255 - wi, 0);
      case 4:  return IN(0, 0, wi);
      default: return IN(2, 255, 255 - wi);
    }
  }
  int hi = h - 1;                     // h in [1,256]
  if (w == 0) {                       // left column
    switch (face) {
      case 0:  return IN(3, hi, 255);
      case 1:  return IN(0, hi, 255);
      case 2:  return IN(1, hi, 255);
      case 3:  return IN(2, hi, 255);
      case 4:  return IN(3, 0, hi);
      default: return IN(3, 255, 255 - hi);
    }
  }
  // right column (w == 257)
  switch (face) {
    case 0:  return IN(1, hi, 0);
    case 1:  return IN(2, hi, 0);
    case 2:  return IN(3, hi, 0);
    case 3:  return IN(0, hi, 0);
    case 4:  return IN(1, 0, 255 - hi);
    default: return IN(1, 255, hi);
  }
#undef IN
}

__global__ void cubepad_v4x4_kernel(const float* __restrict__ x,
                                    float* __restrict__ out) {
  const int t   = threadIdx.x;          // 0..255
  const int fgc = blockIdx.y;           // 0..767
  const int fg  = fgc >> 6;
  const int c   = fgc & 63;
  const int face = fg < 6 ? fg : fg - 6;
  const int nb   = fg < 6 ? 0 : 1;
  const int base_off = nb * 6 * FACE_STRIDE + c * PLANE_IN;
  const float* base = x + base_off;

  const int q0 = blockIdx.x * 1024 + t; // first quad for this thread

  f4 v[4];
  // ---- phase 1: 4 unconditional clamped unaligned 16B loads (MLP=4) ----
#pragma unroll
  for (int k = 0; k < 4; ++k) {
    const int p4 = q0 + (k << 8);
    const unsigned p = (unsigned)p4 << 2;
    const unsigned h = p / WP;          // magic-div by 258
    const unsigned w = p - h * WP;
    int off = base_off + face * FACE_STRIDE + ((int)h - 1) * W_ + ((int)w - 1);
    off = off < 0 ? 0 : off;
    off = off > (TOTAL_IN - 4) ? (TOTAL_IN - 4) : off;
    v[k] = *(const f4u*)(x + off);
  }
  // ---- phase 2: fix up non-interior quads (scalar gather) ----
#pragma unroll
  for (int k = 0; k < 4; ++k) {
    const int p4 = q0 + (k << 8);
    const unsigned p = (unsigned)p4 << 2;
    const unsigned h = p / WP;
    const unsigned w = p - h * WP;
    const bool fast = (h >= 1u) & (h <= 256u) & (w >= 1u) & (w <= 253u);
    if (p4 < P4_PER_PLANE && !fast) {
#pragma unroll
      for (int e = 0; e < 4; ++e) {
        const unsigned pe = p + e;
        const unsigned he = pe / WP;
        const unsigned we = pe - he * WP;
        v[k][e] = value_at(base, face, (int)he, (int)we);
      }
    }
  }
  // ---- phase 3: 4 aligned nontemporal 16B stores ----
  float* oplane = out + (size_t)fgc * PLANE_OUT;
#pragma unroll
  for (int k = 0; k < 4; ++k) {
    const int p4 = q0 + (k << 8);
    if (p4 < P4_PER_PLANE)
      __builtin_nontemporal_store(v[k], (f4*)(oplane + ((size_t)p4 << 2)));
  }
}

extern "C" void kernel_launch(void* const* d_in, const int* in_sizes, int n_in,
                              void* d_out, int out_size, void* d_ws, size_t ws_size,
                              hipStream_t stream) {
  const float* x = (const float*)d_in[0];
  float* out = (float*)d_out;
  dim3 grid((P4_PER_PLANE + 1023) / 1024, 768);   // 17 x 768 blocks
  cubepad_v4x4_kernel<<<grid, 256, 0, stream>>>(x, out);
}